// Round 11
// baseline (600.768 us; speedup 1.0000x reference)
//
#include <hip/hip_runtime.h>

// Problem constants
#define N_     8
#define C_     16
#define T_     300
#define F_     257
#define TF_    (T_*F_)        // 77100
#define CTF_   (C_*TF_)       // 1233600
#define N2CTF_ (2*CTF_)       // per-batch stride in floats (re+im planes)

// K1 tiling
#define FT_    32             // f-tile width
#define NFT_   9              // ceil(257/32)
#define TS_    5              // t's staged per LDS stage (== waves/block)
#define SROW_  34             // 32 y rows (c*2+plane) + 2 x rows (re,im)
#define SSTG_  (SROW_*32)     // floats per staged t = 1088
#define SBUF_  (TS_*SSTG_)    // floats per buffer = 5440 (21.75 KB); x2 = 43.5 KB
#define NTILE_ 10             // lower-triangle 4x4 tiles of the 16x16 Hermitian phi
#define PHIC_  (NTILE_*16)    // 160 float2 stored per (n,f)

#define LOADC  7.0710678118654755e-04f   // 0.001/sqrt(2)

typedef float v2f __attribute__((ext_vector_type(2)));

__device__ __forceinline__ float2 cmul(float2 a, float2 b) {
  return make_float2(a.x*b.x - a.y*b.y, a.x*b.y + a.y*b.x);
}
__device__ __forceinline__ float2 cmulc(float2 a, float2 b) { // a * conj(b)
  return make_float2(a.x*b.x + a.y*b.y, a.y*b.x - a.x*b.y);
}
__device__ __forceinline__ float2 cdiv(float2 a, float2 b) {
  float inv = 1.0f / (b.x*b.x + b.y*b.y);
  return make_float2((a.x*b.x + a.y*b.y)*inv, (a.y*b.x - a.x*b.y)*inv);
}
__device__ __forceinline__ float2 cadd(float2 a, float2 b){ return make_float2(a.x+b.x, a.y+b.y); }
__device__ __forceinline__ float2 csub(float2 a, float2 b){ return make_float2(a.x-b.x, a.y-b.y); }

// Async global->LDS DMA, 4 B per lane. LDS dest is wave-uniform base + lane*4;
// global src is per-lane.
__device__ __forceinline__ void gload4(const float* g, float* l) {
  __builtin_amdgcn_global_load_lds(
      (const __attribute__((address_space(1))) unsigned int*)g,
      (__attribute__((address_space(3))) unsigned int*)l, 4, 0, 0);
}

// Hardware f32 atomic add (global_atomic_add_f32, no CAS loop). Device scope;
// safe across XCDs (learn_hip m20). Used for split-T accumulation.
__device__ __forceinline__ void aadd(float* p, float v) { unsafeAtomicAdd(p, v); }
__device__ __forceinline__ void aadd2(float2* p, v2f v) {
  unsafeAtomicAdd(&p->x, v.x); unsafeAtomicAdd(&p->y, v.y);
}

// ---------------------------------------------------------------------------
// K1 v10: frozen v6 pipeline (R1 structure, TCP=10 -- 60.0-60.8 us across
// R5/R6/R7/R10; VGPR 96, zero spill); epilogue changed from per-chunk partial
// STORES to device-scope ATOMIC accumulation into the final (n,f) sums
// (split-K pattern). Kills the 31 MB partial write + 42 MB k2 re-read; the
// sum region is zeroed by a hipMemsetAsync before launch. Chunk-add ordering
// becomes nondeterministic -- tolerance-safe (chunk order was arbitrary
// already). History: R2 ring (spills, 82us), R3 TS=4 (scratch, 261us), R4
// direct-load (no MLP, 110us), R5 TCP=12 (tail, 67us). Pipeline FROZEN.
// ---------------------------------------------------------------------------
template<int TCH>
__global__ __launch_bounds__(320) void k1_cov(const float* __restrict__ mix,
                                              const float* __restrict__ tgt,
                                              float2* __restrict__ phi_p,
                                              float2* __restrict__ syx_p,
                                              float2* __restrict__ sy_p,
                                              float2* __restrict__ sx_p) {
  __shared__ float ys[2 * SBUF_];
  const int tid = threadIdx.x;
  const int ft = blockIdx.x, tc = blockIdx.y, n = blockIdx.z;
  const int fbase = ft * FT_;
  const int t0 = tc * TCH;
  const int fl = tid & 31;
  const int g  = tid >> 5;          // 0..9 == canonical lower-tri tile index
  int ti = 0, tj = g;               // lower-triangle tile decode, ti>=tj
  while (tj > ti) { ++ti; tj -= ti; }
  const int c0 = ti * 4;
  const int d0 = tj * 4;
  const bool sThread = (tj == 0);   // tiles (0..3,0): c0 covers 0,4,8,12

  // staging decode: wave w stages ts=w; lane = plane*32 + fl
  const int w     = tid >> 6;           // 0..4 (uniform per wave)
  const int plane = (tid >> 5) & 1;     // 0 = re, 1 = im
  const int f_ld  = min(fbase + fl, F_ - 1);   // clamped OOB f

  const float* mixN = mix + n * N2CTF_;
  const float* tgtN = tgt + n * N2CTF_;
  const float* ysrc = mixN + plane * CTF_ + (t0 + w) * F_ + f_ld;  // c=0, s=0
  const float* xsrc = tgtN + plane * CTF_ + (t0 + w) * F_ + f_ld;  // ref mic

  v2f acc[4][4];
  #pragma unroll
  for (int i = 0; i < 4; ++i)
    #pragma unroll
    for (int j = 0; j < 4; ++j) acc[i][j] = (v2f){0.f, 0.f};
  v2f syx[4], sy[4], sx = (v2f){0.f, 0.f};
  #pragma unroll
  for (int i = 0; i < 4; ++i) { syx[i] = (v2f){0.f,0.f}; sy[i] = (v2f){0.f,0.f}; }

  constexpr int NS = TCH / TS_;
  static_assert(NS * TS_ == TCH, "TCH must be a multiple of TS_");

  // prologue: issue stage-0 DMA into buffer 0
  {
    float* dst = &ys[w * SSTG_];
    #pragma unroll
    for (int c = 0; c < 16; ++c) gload4(ysrc + c * TF_, dst + 2 * c * 32);
    gload4(xsrc, dst + 32 * 32);
  }

  for (int s = 0; s < NS; ++s) {
    __syncthreads();                 // vmcnt(0)+barrier: buf[s&1] ready everywhere
    if (s + 1 < NS) {                // issue next-stage DMA (drains at next barrier)
      float* dst = &ys[((s + 1) & 1) * SBUF_ + w * SSTG_];
      const float* yp = ysrc + (s + 1) * (TS_ * F_);
      #pragma unroll
      for (int c = 0; c < 16; ++c) gload4(yp + c * TF_, dst + 2 * c * 32);
      gload4(xsrc + (s + 1) * (TS_ * F_), dst + 32 * 32);
    }
    const float* bufc = &ys[(s & 1) * SBUF_];
    #pragma unroll
    for (int tl = 0; tl < TS_; ++tl) {
      const float* rt = bufc + tl * SSTG_;
      v2f a[4], bu[4], bv[4];
      #pragma unroll
      for (int i = 0; i < 4; ++i) {
        float re = rt[(2 * (c0 + i)) * 32 + fl];
        float im = rt[(2 * (c0 + i)) * 32 + 32 + fl];
        a[i] = (v2f){re, im};
      }
      #pragma unroll
      for (int j = 0; j < 4; ++j) {
        float re = rt[(2 * (d0 + j)) * 32 + fl];
        float im = rt[(2 * (d0 + j)) * 32 + 32 + fl];
        bu[j] = (v2f){re, -im};            // for y_c * conj(y_d)
        bv[j] = (v2f){im,  re};
      }
      #pragma unroll
      for (int i = 0; i < 4; ++i)
        #pragma unroll
        for (int j = 0; j < 4; ++j)
          acc[i][j] += a[i].x * bu[j] + a[i].y * bv[j];
      if (sThread) {
        float xre = rt[32 * 32 + fl];
        float xim = rt[33 * 32 + fl];
        v2f xu = (v2f){xre, -xim};
        v2f xw = (v2f){xim,  xre};
        #pragma unroll
        for (int i = 0; i < 4; ++i) {
          syx[i] += a[i].x * xu + a[i].y * xw;   // y_c * conj(x0)
          sy[i]  += a[i];
        }
        if (g == 0) sx += (v2f){xre, xim};
      }
    }
  }

  const int f = fbase + fl;
  if (f < F_) {
    // atomic accumulation into FINAL (n,f) sums (no tc dimension).
    float2* pb = phi_p + ((size_t)(n * F_ + f)) * PHIC_ + g * 16;
    #pragma unroll
    for (int i = 0; i < 4; ++i)
      #pragma unroll
      for (int j = 0; j < 4; ++j) aadd2(pb + i * 4 + j, acc[i][j]);
    if (sThread) {
      float2* s1 = syx_p + ((size_t)(n * F_ + f)) * C_ + c0;
      float2* s2 = sy_p  + ((size_t)(n * F_ + f)) * C_ + c0;
      #pragma unroll
      for (int i = 0; i < 4; ++i) { aadd2(s1 + i, syx[i]); aadd2(s2 + i, sy[i]); }
      if (g == 0) aadd2(sx_p + (size_t)n * F_ + f, sx);
    }
  }
}

// ---------------------------------------------------------------------------
// K2 fused v2: final-sum gather + rhs + in-block Gauss-Jordan.
// grid (F_, N_) = 2056 blocks (full occupancy -- R7 proved 257-block variant
// is +10.7us latency-bound). Reads are now ~4 MB total (final sums) instead
// of 67 MB of chunk partials. GJ structure byte-identical to the verified
// solver. Writes planar wre/wim (old scalar k3's layout).
// ---------------------------------------------------------------------------
__global__ __launch_bounds__(256) void k2_fused(const float2* __restrict__ phi_p,
                                                const float2* __restrict__ syx_p,
                                                const float2* __restrict__ sy_p,
                                                const float2* __restrict__ sx_p,
                                                float* __restrict__ wre,
                                                float* __restrict__ wim) {
  __shared__ float2 Msh[16 * 17];
  __shared__ float2 muB_s, sxO_s;
  const int f = blockIdx.x, n = blockIdx.y;
  const int tid = threadIdx.x;
  const int i = tid >> 4, j = tid & 15;

  // Hermitian mirror: (i,j) in lower tile (ti,tj) directly, else conj (j,i).
  const int ti = i >> 2, tj = j >> 2, ci = i & 3, cj = j & 3;
  int gL, cell; bool cj_flip;
  if (ti >= tj) { gL = ti * (ti + 1) / 2 + tj; cell = ci * 4 + cj; cj_flip = false; }
  else          { gL = tj * (tj + 1) / 2 + ti; cell = cj * 4 + ci; cj_flip = true; }
  const int off = gL * 16 + cell;

  float2 s = phi_p[((size_t)(n * F_ + f)) * PHIC_ + off];
  if (cj_flip) s.y = -s.y;
  if (i == j) { s.x += (float)T_ * LOADC; s.y += (float)T_ * LOADC; }
  Msh[i * 17 + j] = s;

  float2 muA_r = make_float2(0.f,0.f), ownY = make_float2(0.f,0.f), ownYX = make_float2(0.f,0.f);
  if (tid < 16) {
    float2 allY = make_float2(0.f,0.f);
    for (int nn = 0; nn < N_; ++nn)
      allY = cadd(allY, sy_p[((size_t)(nn * F_ + f)) * C_ + tid]);
    ownY  = sy_p[((size_t)(n * F_ + f)) * C_ + tid];
    ownYX = syx_p[((size_t)(n * F_ + f)) * C_ + tid];
    const float invNT = 1.0f / ((float)N_ * (float)T_);
    muA_r = make_float2(allY.x * invNT, allY.y * invNT);
  }
  if (tid == 16) {
    float2 all = make_float2(0.f,0.f);
    for (int nn = 0; nn < N_; ++nn) all = cadd(all, sx_p[(size_t)nn * F_ + f]);
    const float invNT = 1.0f / ((float)N_ * (float)T_);
    muB_s = make_float2(all.x * invNT, all.y * invNT);
    sxO_s = sx_p[(size_t)n * F_ + f];
  }
  __syncthreads();   // uniform: M staged + muB/sxO published

  if (tid < 16) {
    // rhs = S_yx - muA*conj(S_x_own) - conj(muB)*S_y_own + T*muA*conj(muB)
    float2 r = ownYX;
    r = csub(r, cmulc(muA_r, sxO_s));
    r = csub(r, cmulc(ownY, muB_s));
    float2 t3 = cmulc(muA_r, muB_s);
    r.x += (float)T_ * t3.x; r.y += (float)T_ * t3.y;
    Msh[tid * 17 + 16] = r;
  }
  __syncthreads();   // uniform: matrix + rhs assembled

  // Gauss-Jordan, no pivoting (diag-dominant). Same op order as verified k2b.
  for (int k = 0; k < 16; ++k) {
    float2 fac = cdiv(Msh[i * 17 + k], Msh[k * 17 + k]);
    __syncthreads();
    if (i != k) {
      Msh[i * 17 + j] = csub(Msh[i * 17 + j], cmul(fac, Msh[k * 17 + j]));
      if (j == 15) Msh[i * 17 + 16] = csub(Msh[i * 17 + 16], cmul(fac, Msh[k * 17 + 16]));
    }
    __syncthreads();
  }
  if (j == 0) {
    float2 wv = cdiv(Msh[i * 17 + 16], Msh[i * 17 + i]);
    wre[(n * C_ + i) * F_ + f] = wv.x;
    wim[(n * C_ + i) * F_ + f] = wv.y;
  }
}

// ---------------------------------------------------------------------------
// K3 v5 (verbatim best-measured): beamform, 2 t's per block. grid (T_/2, N_)
// = 1200 blocks x 320 thr (~23 waves/CU). f = tid single-pass.
// R6 DMA-staged: +9us. R10 float4+divergent-remainder: +20us (per-wave VMEM
// instruction storm from 1-lane exec paths). High-TLP scalar wins. FROZEN.
// ---------------------------------------------------------------------------
__global__ __launch_bounds__(320) void k3_bf(const float* __restrict__ mix,
                                             const float* __restrict__ wre,
                                             const float* __restrict__ wim,
                                             float* __restrict__ out) {
  const int t0 = blockIdx.x * 2, n = blockIdx.y;
  const int f = threadIdx.x;
  if (f >= F_) return;
  const float* mixN = mix + n * N2CTF_;
  const float* wR = wre + n * C_ * F_;
  const float* wI = wim + n * C_ * F_;
  float* outN = out + n * 2 * TF_;
  float wr[16], wi[16];
  #pragma unroll
  for (int c = 0; c < 16; ++c) { wr[c] = wR[c * F_ + f]; wi[c] = wI[c * F_ + f]; }
  const float* yb = mixN + t0 * F_ + f;
  float xr0 = 0.f, xi0 = 0.f, xr1 = 0.f, xi1 = 0.f;
  #pragma unroll
  for (int c = 0; c < 16; ++c) {
    float yr0 = yb[c * TF_],      yi0 = yb[CTF_ + c * TF_];
    float yr1 = yb[c * TF_ + F_], yi1 = yb[CTF_ + c * TF_ + F_];
    xr0 += wr[c] * yr0 + wi[c] * yi0;   // conj(w)*y
    xi0 += wr[c] * yi0 - wi[c] * yr0;
    xr1 += wr[c] * yr1 + wi[c] * yi1;
    xi1 += wr[c] * yi1 - wi[c] * yr1;
  }
  outN[t0 * F_ + f] = xr0;
  outN[TF_ + t0 * F_ + f] = xi0;
  outN[(t0 + 1) * F_ + f] = xr1;
  outN[TF_ + (t0 + 1) * F_ + f] = xi1;
}

// ---------------------------------------------------------------------------
// ws layout (float2 units): phi (N*F*PHIC) | syx (N*F*C) | sy (N*F*C) |
// sx (N*F) | then wre/wim floats. The sum prefix (3.17 MB) is zeroed by a
// hipMemsetAsync each launch (required: atomics accumulate).
// ---------------------------------------------------------------------------
#define SUMF2_ ((size_t)N_ * F_ * (PHIC_ + 2 * C_ + 1))

static void launch_all(const float* mix, const float* tgt, float* ws, float* out,
                       hipStream_t stream) {
  constexpr int TCP = 10, TCH = T_ / TCP;
  float2* phi_p = (float2*)ws;
  float2* syx_p = phi_p + (size_t)N_ * F_ * PHIC_;
  float2* sy_p  = syx_p + (size_t)N_ * F_ * C_;
  float2* sx_p  = sy_p  + (size_t)N_ * F_ * C_;
  float*  wre   = (float*)(sx_p + (size_t)N_ * F_);
  float*  wim   = wre + N_ * C_ * F_;
  hipMemsetAsync(ws, 0, SUMF2_ * sizeof(float2), stream);
  k1_cov<TCH><<<dim3(NFT_, TCP, N_), dim3(320), 0, stream>>>(mix, tgt, phi_p, syx_p, sy_p, sx_p);
  k2_fused<<<dim3(F_, N_), dim3(256), 0, stream>>>(phi_p, syx_p, sy_p, sx_p, wre, wim);
  k3_bf<<<dim3(T_ / 2, N_), dim3(320), 0, stream>>>(mix, wre, wim, out);
}

extern "C" void kernel_launch(void* const* d_in, const int* in_sizes, int n_in,
                              void* d_out, int out_size, void* d_ws, size_t ws_size,
                              hipStream_t stream) {
  const float* mix = (const float*)d_in[0];
  const float* tgt = (const float*)d_in[1];
  // d_in[2] (steering_vector) is unused by the reference.
  launch_all(mix, tgt, (float*)d_ws, (float*)d_out, stream);
}